// Round 1
// baseline (893.421 us; speedup 1.0000x reference)
//
#include <hip/hip_runtime.h>
#include <hip/hip_bf16.h>

typedef __bf16 bf16x8 __attribute__((ext_vector_type(8)));
typedef float f32x4 __attribute__((ext_vector_type(4)));

#define BN_EPS 1e-5f

// ---------------- K0: fp32 -> bf16 conversion ----------------
__global__ void cvt_kernel(const float* __restrict__ a, __bf16* __restrict__ o, int n) {
    int i = blockIdx.x * blockDim.x + threadIdx.x;
    int stride = gridDim.x * blockDim.x;
    for (; i < n; i += stride) o[i] = (__bf16)a[i];
}

// ---------------- K12: fused conv1+bn+relu+conv2+bn+relu+haar+attn -> f ----------------
// one block per image, 256 threads
__global__ __launch_bounds__(256) void conv_fused_kernel(
    const float* __restrict__ x,
    const float* __restrict__ w1, const float* __restrict__ b1,
    const float* __restrict__ g1, const float* __restrict__ be1,
    const float* __restrict__ m1, const float* __restrict__ v1,
    const float* __restrict__ w2, const float* __restrict__ b2,
    const float* __restrict__ g2, const float* __restrict__ be2,
    const float* __restrict__ m2, const float* __restrict__ v2,
    const float* __restrict__ wa, const float* __restrict__ ba,
    __bf16* __restrict__ f)
{
    __shared__ float  xs[3][32][32];     // 12 KB
    __shared__ __bf16 hs[32][16][16];    // 16 KB
    __shared__ float  feat_s[64][64];    // 16 KB  [c][pixel]
    __shared__ float  cd_s[64][16];      // 4 KB
    __shared__ float  attn_s[4][64];     // 1 KB

    const int b   = blockIdx.x;
    const int tid = threadIdx.x;

    // stage input image (3*32*32 fp32 = 768 float4)
    {
        const float4* xb = (const float4*)(x + (size_t)b * 3072);
        float4* xsd = (float4*)&xs[0][0][0];
        #pragma unroll
        for (int r = 0; r < 3; ++r) xsd[r * 256 + tid] = xb[r * 256 + tid];
    }
    __syncthreads();

    // ---- conv1 5x5 s2 p2: thread = one output pixel, loops 32 oc in 4 groups of 8 ----
    {
        const int oy = tid >> 4, ox = tid & 15;
        for (int ocg = 0; ocg < 4; ++ocg) {
            float acc[8];
            #pragma unroll
            for (int j = 0; j < 8; ++j) acc[j] = 0.f;
            for (int ic = 0; ic < 3; ++ic) {
                #pragma unroll
                for (int ky = 0; ky < 5; ++ky) {
                    int iy  = 2 * oy - 2 + ky;
                    int iyc = min(max(iy, 0), 31);
                    bool yok = (iy >= 0) && (iy < 32);
                    float xv[5];
                    #pragma unroll
                    for (int kx = 0; kx < 5; ++kx) {
                        int ix  = 2 * ox - 2 + kx;
                        int ixc = min(max(ix, 0), 31);
                        bool ok = yok && (ix >= 0) && (ix < 32);
                        float val = xs[ic][iyc][ixc];
                        xv[kx] = ok ? val : 0.f;
                    }
                    #pragma unroll
                    for (int j = 0; j < 8; ++j) {
                        // uniform index -> scalar loads (SGPR operand FMAs)
                        const float* wp = w1 + (((ocg * 8 + j) * 3 + ic) * 5 + ky) * 5;
                        #pragma unroll
                        for (int kx = 0; kx < 5; ++kx) acc[j] += xv[kx] * wp[kx];
                    }
                }
            }
            #pragma unroll
            for (int j = 0; j < 8; ++j) {
                int oc = ocg * 8 + j;
                float inv = g1[oc] * rsqrtf(v1[oc] + BN_EPS);
                float bb  = be1[oc] + (b1[oc] - m1[oc]) * inv;
                float v   = fmaxf(acc[j] * inv + bb, 0.f);
                hs[oc][oy][ox] = (__bf16)v;
            }
        }
    }
    __syncthreads();

    // ---- conv2 3x3 s2 p1 + bn + relu ----
    // thread = (pixel q in 8x8, oc group g of 16); g is wave-uniform -> scalar weight loads
    const int q  = tid & 63;
    const int g  = __builtin_amdgcn_readfirstlane(tid >> 6);
    const int qy = q >> 3, qx = q & 7;
    float a2[16];
    #pragma unroll
    for (int j = 0; j < 16; ++j) a2[j] = 0.f;
    for (int ic = 0; ic < 32; ++ic) {
        float hv[9];
        #pragma unroll
        for (int ky = 0; ky < 3; ++ky) {
            int iy  = 2 * qy - 1 + ky;   // in [-1, 15]
            int iyc = max(iy, 0);
            #pragma unroll
            for (int kx = 0; kx < 3; ++kx) {
                int ix  = 2 * qx - 1 + kx;  // in [-1, 15]
                int ixc = max(ix, 0);
                bool ok = (iy >= 0) && (ix >= 0);
                float hval = (float)hs[ic][iyc][ixc];
                hv[ky * 3 + kx] = ok ? hval : 0.f;
            }
        }
        #pragma unroll
        for (int j = 0; j < 16; ++j) {
            const float* wp = w2 + ((g * 16 + j) * 32 + ic) * 9;
            #pragma unroll
            for (int t = 0; t < 9; ++t) a2[j] += hv[t] * wp[t];
        }
    }
    #pragma unroll
    for (int j = 0; j < 16; ++j) {
        int oc = g * 16 + j;
        float inv = g2[oc] * rsqrtf(v2[oc] + BN_EPS);
        float bb  = be2[oc] + (b2[oc] - m2[oc]) * inv;
        float v   = fmaxf(a2[j] * inv + bb, 0.f);
        a2[j] = v;
        feat_s[oc][q] = v;
    }
    __syncthreads();

    // ---- Haar cD: cd[c][y][x] = 0.5*(f[2y][2x]-f[2y][2x+1]-f[2y+1][2x]+f[2y+1][2x+1]) ----
    #pragma unroll
    for (int r = 0; r < 4; ++r) {
        int idx = tid * 4 + r;            // 0..1023 = 64c x 16yx
        int c = idx >> 4, yx = idx & 15;
        int y = yx >> 2, xx = yx & 3;
        float aa  = feat_s[c][(2 * y) * 8 + 2 * xx];
        float bb2 = feat_s[c][(2 * y) * 8 + 2 * xx + 1];
        float cc  = feat_s[c][(2 * y + 1) * 8 + 2 * xx];
        float dd  = feat_s[c][(2 * y + 1) * 8 + 2 * xx + 1];
        cd_s[c][yx] = 0.5f * (aa - bb2 - cc + dd);
    }
    __syncthreads();

    // ---- feat *= cD_up ; attention logits (1x1 conv) ----
    const int qq = (qy >> 1) * 4 + (qx >> 1);
    float part = 0.f;
    #pragma unroll
    for (int j = 0; j < 16; ++j) {
        int oc = g * 16 + j;
        float v = a2[j] * cd_s[oc][qq];
        a2[j] = v;
        part += v * wa[oc];
    }
    attn_s[g][q] = part;
    __syncthreads();
    float s   = attn_s[0][q] + attn_s[1][q] + attn_s[2][q] + attn_s[3][q] + ba[0];
    float sig = 1.f / (1.f + __expf(-s));

    // ---- write f[b][c*64 + q] (bf16) ----
    __bf16* fb = f + (size_t)b * 4096;
    #pragma unroll
    for (int j = 0; j < 16; ++j) {
        fb[(g * 16 + j) * 64 + q] = (__bf16)(a2[j] * sig);
    }
}

// ---------------- K3: dense1 GEMM: C[8192,512] = relu(A[8192,4096] @ B[512,4096]^T + bd1) ----------------
// tile 128(M) x 64(N), BK=64, 256 threads = 4 waves (2x2), wave tile 64x32 = 4x2 MFMA 16x16x32
__global__ __launch_bounds__(256) void gemm1_kernel(
    const __bf16* __restrict__ A, const __bf16* __restrict__ B,
    const float* __restrict__ bias, __bf16* __restrict__ C)
{
    const int K = 4096, NOUT = 512;
    __shared__ __align__(16) __bf16 As[128][72];  // +8 pad: conflict-free frag reads
    __shared__ __align__(16) __bf16 Bs[64][72];
    const int tid  = threadIdx.x;
    const int lane = tid & 63;
    const int wave = tid >> 6;
    const int wm = wave >> 1, wn = wave & 1;
    const int m0 = blockIdx.x * 128, n0 = blockIdx.y * 64;
    f32x4 acc[4][2] = {};
    for (int k0 = 0; k0 < K; k0 += 64) {
        #pragma unroll
        for (int r = 0; r < 4; ++r) {      // A: 128 rows x 64 cols = 1024 16B chunks
            int i = r * 256 + tid;
            int row = i >> 3, gg = i & 7;
            *(bf16x8*)(&As[row][gg * 8]) = *(const bf16x8*)(A + (size_t)(m0 + row) * K + k0 + gg * 8);
        }
        #pragma unroll
        for (int r = 0; r < 2; ++r) {      // B: 64 rows x 64 cols = 512 chunks
            int i = r * 256 + tid;
            int row = i >> 3, gg = i & 7;
            *(bf16x8*)(&Bs[row][gg * 8]) = *(const bf16x8*)(B + (size_t)(n0 + row) * K + k0 + gg * 8);
        }
        __syncthreads();
        #pragma unroll
        for (int s = 0; s < 2; ++s) {
            int kk = s * 32 + (lane >> 4) * 8;
            bf16x8 af[4], bfr[2];
            #pragma unroll
            for (int mt = 0; mt < 4; ++mt)
                af[mt] = *(const bf16x8*)(&As[wm * 64 + mt * 16 + (lane & 15)][kk]);
            #pragma unroll
            for (int nt = 0; nt < 2; ++nt)
                bfr[nt] = *(const bf16x8*)(&Bs[wn * 32 + nt * 16 + (lane & 15)][kk]);
            #pragma unroll
            for (int mt = 0; mt < 4; ++mt)
                #pragma unroll
                for (int nt = 0; nt < 2; ++nt)
                    acc[mt][nt] = __builtin_amdgcn_mfma_f32_16x16x32_bf16(af[mt], bfr[nt], acc[mt][nt], 0, 0, 0);
        }
        __syncthreads();
    }
    #pragma unroll
    for (int mt = 0; mt < 4; ++mt)
        #pragma unroll
        for (int nt = 0; nt < 2; ++nt)
            #pragma unroll
            for (int r = 0; r < 4; ++r) {
                int m = m0 + wm * 64 + mt * 16 + (lane >> 4) * 4 + r;
                int n = n0 + wn * 32 + nt * 16 + (lane & 15);
                float v = acc[mt][nt][r] + bias[n];
                C[(size_t)m * NOUT + n] = (__bf16)fmaxf(v, 0.f);
            }
}

// ---------------- K4: dense2: out[8192,128] = sigmoid(A[8192,512] @ B[128,512]^T + bd2), fp32 out ----------------
// tile 64(M) x 128(N=all), BK=64, 4 waves along N, wave tile 64x32
__global__ __launch_bounds__(256) void gemm2_kernel(
    const __bf16* __restrict__ A, const __bf16* __restrict__ B,
    const float* __restrict__ bias, float* __restrict__ Out)
{
    const int K = 512, NOUT = 128;
    __shared__ __align__(16) __bf16 As[64][72];
    __shared__ __align__(16) __bf16 Bs[128][72];
    const int tid  = threadIdx.x;
    const int lane = tid & 63;
    const int wave = tid >> 6;
    const int m0 = blockIdx.x * 64;
    f32x4 acc[4][2] = {};
    for (int k0 = 0; k0 < K; k0 += 64) {
        #pragma unroll
        for (int r = 0; r < 2; ++r) {      // A: 64x64 = 512 chunks
            int i = r * 256 + tid;
            int row = i >> 3, gg = i & 7;
            *(bf16x8*)(&As[row][gg * 8]) = *(const bf16x8*)(A + (size_t)(m0 + row) * K + k0 + gg * 8);
        }
        #pragma unroll
        for (int r = 0; r < 4; ++r) {      // B: 128x64 = 1024 chunks
            int i = r * 256 + tid;
            int row = i >> 3, gg = i & 7;
            *(bf16x8*)(&Bs[row][gg * 8]) = *(const bf16x8*)(B + (size_t)row * K + k0 + gg * 8);
        }
        __syncthreads();
        #pragma unroll
        for (int s = 0; s < 2; ++s) {
            int kk = s * 32 + (lane >> 4) * 8;
            bf16x8 af[4], bfr[2];
            #pragma unroll
            for (int mt = 0; mt < 4; ++mt)
                af[mt] = *(const bf16x8*)(&As[mt * 16 + (lane & 15)][kk]);
            #pragma unroll
            for (int nt = 0; nt < 2; ++nt)
                bfr[nt] = *(const bf16x8*)(&Bs[wave * 32 + nt * 16 + (lane & 15)][kk]);
            #pragma unroll
            for (int mt = 0; mt < 4; ++mt)
                #pragma unroll
                for (int nt = 0; nt < 2; ++nt)
                    acc[mt][nt] = __builtin_amdgcn_mfma_f32_16x16x32_bf16(af[mt], bfr[nt], acc[mt][nt], 0, 0, 0);
        }
        __syncthreads();
    }
    #pragma unroll
    for (int mt = 0; mt < 4; ++mt)
        #pragma unroll
        for (int nt = 0; nt < 2; ++nt)
            #pragma unroll
            for (int r = 0; r < 4; ++r) {
                int m = m0 + mt * 16 + (lane >> 4) * 4 + r;
                int n = wave * 32 + nt * 16 + (lane & 15);
                float v = acc[mt][nt][r] + bias[n];
                Out[(size_t)m * NOUT + n] = 1.f / (1.f + __expf(-v));
            }
}

extern "C" void kernel_launch(void* const* d_in, const int* in_sizes, int n_in,
                              void* d_out, int out_size, void* d_ws, size_t ws_size,
                              hipStream_t stream)
{
    const float* x   = (const float*)d_in[0];
    const float* w1  = (const float*)d_in[1];
    const float* b1  = (const float*)d_in[2];
    const float* g1  = (const float*)d_in[3];
    const float* be1 = (const float*)d_in[4];
    const float* m1  = (const float*)d_in[5];
    const float* v1  = (const float*)d_in[6];
    const float* w2  = (const float*)d_in[7];
    const float* b2  = (const float*)d_in[8];
    const float* g2  = (const float*)d_in[9];
    const float* be2 = (const float*)d_in[10];
    const float* m2  = (const float*)d_in[11];
    const float* v2  = (const float*)d_in[12];
    const float* wa  = (const float*)d_in[13];
    const float* ba  = (const float*)d_in[14];
    const float* wd1 = (const float*)d_in[15];
    const float* bd1 = (const float*)d_in[16];
    const float* wd2 = (const float*)d_in[17];
    const float* bd2 = (const float*)d_in[18];

    char* ws = (char*)d_ws;
    __bf16* f_bf   = (__bf16*)(ws);                                   // 8192*4096*2 = 64 MiB
    __bf16* h1_bf  = (__bf16*)(ws + 67108864);                        // 8192*512*2  =  8 MiB
    __bf16* wd1_bf = (__bf16*)(ws + 67108864 + 8388608);              // 512*4096*2  =  4 MiB
    __bf16* wd2_bf = (__bf16*)(ws + 67108864 + 8388608 + 4194304);    // 128*512*2

    cvt_kernel<<<2048, 256, 0, stream>>>(wd1, wd1_bf, 512 * 4096);
    cvt_kernel<<<64, 256, 0, stream>>>(wd2, wd2_bf, 128 * 512);

    conv_fused_kernel<<<8192, 256, 0, stream>>>(x, w1, b1, g1, be1, m1, v1,
                                                w2, b2, g2, be2, m2, v2, wa, ba, f_bf);

    dim3 g3(64, 8);
    gemm1_kernel<<<g3, 256, 0, stream>>>(f_bf, wd1_bf, bd1, h1_bf);

    gemm2_kernel<<<128, 256, 0, stream>>>(h1_bf, wd2_bf, bd2, (float*)d_out);
}

// Round 2
// 558.157 us; speedup vs baseline: 1.6007x; 1.6007x over previous
//
#include <hip/hip_runtime.h>
#include <hip/hip_bf16.h>

typedef __bf16 bf16x8 __attribute__((ext_vector_type(8)));
typedef float f32x4 __attribute__((ext_vector_type(4)));

#define BN_EPS 1e-5f

// ---------------- K0: fp32 -> bf16 conversion ----------------
__global__ void cvt_kernel(const float* __restrict__ a, __bf16* __restrict__ o, int n) {
    int i = blockIdx.x * blockDim.x + threadIdx.x;
    int stride = gridDim.x * blockDim.x;
    for (; i < n; i += stride) o[i] = (__bf16)a[i];
}

// ---------------- K0b: reorder w2 [oc][ic][tap] -> [oc][tap][ic] bf16 ----------------
__global__ void w2r_kernel(const float* __restrict__ w2, __bf16* __restrict__ o) {
    int i = blockIdx.x * 256 + threadIdx.x;
    if (i < 64 * 288) {
        int oc = i / 288, rem = i % 288;
        int tap = rem / 32, ic = rem % 32;
        o[i] = (__bf16)w2[(oc * 32 + ic) * 9 + tap];
    }
}

// ---------------- K12: fused conv1(VALU)+bn+relu + conv2(MFMA)+bn+relu + haar+attn -> f ----------------
// one block per image, 256 threads = 4 waves. LDS 40000 B -> 4 blocks/CU.
__global__ __launch_bounds__(256) void conv_fused_kernel(
    const float* __restrict__ x,
    const float* __restrict__ w1, const float* __restrict__ b1,
    const float* __restrict__ g1, const float* __restrict__ be1,
    const float* __restrict__ m1, const float* __restrict__ v1,
    const __bf16* __restrict__ w2r, const float* __restrict__ b2,
    const float* __restrict__ g2, const float* __restrict__ be2,
    const float* __restrict__ m2, const float* __restrict__ v2,
    const float* __restrict__ wa, const float* __restrict__ ba,
    __bf16* __restrict__ f)
{
    struct SMemB {
        float feat[64][64];   // [oc][pixel] fp32
        float cd[64][16];
        float attn[4][64];
    };
    // hs: conv1 output, channel-last, +1 zero border on top/left (pad=1 conv2)
    __shared__ __align__(16) __bf16 hs[17][17][32];                 // 18496 B
    __shared__ __align__(16) union { float xs[3][36][40]; SMemB pb; } u;  // 21504 B

    const int b    = blockIdx.x;
    const int tid  = threadIdx.x;
    const int lane = tid & 63;
    const int wave = tid >> 6;
    const int wm   = wave >> 1, wn = wave & 1;
    const int lo   = lane >> 4;      // k-octet / row group within MFMA
    const int ln   = lane & 15;

    // ---- zero-fill padded xs and hs border ----
    {
        float* xp = &u.xs[0][0][0];
        #pragma unroll
        for (int i = tid; i < 3 * 36 * 40; i += 256) xp[i] = 0.f;
        if (tid < 132) {
            bf16x8 z = {};
            if (tid < 68) { int col = tid >> 2, o = tid & 3; *(bf16x8*)&hs[0][col][o * 8] = z; }
            else { int cc = tid - 68; int row = 1 + (cc >> 2), o = cc & 3; *(bf16x8*)&hs[row][0][o * 8] = z; }
        }
    }
    __syncthreads();

    // ---- stage x into padded xs: logical x[ic][y][xx] -> xs[ic][y+2][xx+4] ----
    {
        const float4* xb = (const float4*)(x + (size_t)b * 3072);
        #pragma unroll
        for (int r = 0; r < 3; ++r) {
            int c = r * 256 + tid;              // 0..767
            int plane = c >> 8, rem = c & 255;
            int row = rem >> 3, c4 = rem & 7;
            *(float4*)&u.xs[plane][row + 2][4 + c4 * 4] = xb[c];
        }
    }
    __syncthreads();

    // ---- conv1 5x5 s2 p2 (VALU): thread = output pixel (16x16), all 32 oc ----
    {
        const int oy = tid >> 4, ox = tid & 15;
        float acc[32];
        #pragma unroll
        for (int j = 0; j < 32; ++j) acc[j] = 0.f;
        for (int ic = 0; ic < 3; ++ic) {
            #pragma unroll
            for (int ky = 0; ky < 5; ++ky) {
                float xv[5];
                #pragma unroll
                for (int kx = 0; kx < 5; ++kx)
                    xv[kx] = u.xs[ic][2 * oy + ky][2 * ox + kx + 2];
                for (int ocg = 0; ocg < 4; ++ocg) {
                    #pragma unroll
                    for (int j = 0; j < 8; ++j) {
                        const float* wp = w1 + (((ocg * 8 + j) * 3 + ic) * 5 + ky) * 5;
                        #pragma unroll
                        for (int kx = 0; kx < 5; ++kx)
                            acc[ocg * 8 + j] = fmaf(xv[kx], wp[kx], acc[ocg * 8 + j]);
                    }
                }
            }
        }
        // BN + ReLU -> bf16, channel-last store (4x ds_write_b128)
        #pragma unroll
        for (int o = 0; o < 4; ++o) {
            bf16x8 hv;
            #pragma unroll
            for (int j = 0; j < 8; ++j) {
                int oc = o * 8 + j;
                float inv = g1[oc] * rsqrtf(v1[oc] + BN_EPS);
                float bb  = be1[oc] + (b1[oc] - m1[oc]) * inv;
                hv[j] = (__bf16)fmaxf(acc[oc] * inv + bb, 0.f);
            }
            *(bf16x8*)&hs[oy + 1][ox + 1][o * 8] = hv;
        }
    }

    // ---- preload conv2 B-fragments (w2r from L2), 18 x 16B per lane ----
    bf16x8 bfr[2][9];
    #pragma unroll
    for (int nt = 0; nt < 2; ++nt) {
        int oc = wn * 32 + nt * 16 + ln;
        const __bf16* wp = w2r + oc * 288 + lo * 8;
        #pragma unroll
        for (int ks = 0; ks < 9; ++ks)
            bfr[nt][ks] = *(const bf16x8*)(wp + ks * 32);
    }
    __syncthreads();

    // ---- conv2 3x3 s2 p1 as MFMA: M=64 pix, N=64 oc, K=288 (tap-major, ic fast) ----
    f32x4 cacc[2][2] = {};
    #pragma unroll
    for (int ks = 0; ks < 9; ++ks) {
        const int ty = ks / 3, tx = ks % 3;
        bf16x8 af[2];
        #pragma unroll
        for (int mt = 0; mt < 2; ++mt) {
            int p  = wm * 32 + mt * 16 + ln;
            int qy = p >> 3, qx = p & 7;
            af[mt] = *(const bf16x8*)&hs[2 * qy + ty][2 * qx + tx][lo * 8];
        }
        #pragma unroll
        for (int mt = 0; mt < 2; ++mt)
            #pragma unroll
            for (int nt = 0; nt < 2; ++nt)
                cacc[mt][nt] = __builtin_amdgcn_mfma_f32_16x16x32_bf16(af[mt], bfr[nt][ks], cacc[mt][nt], 0, 0, 0);
    }

    // ---- BN + ReLU -> feat[oc][pixel] in LDS ----
    #pragma unroll
    for (int nt = 0; nt < 2; ++nt) {
        int oc = wn * 32 + nt * 16 + ln;
        float inv = g2[oc] * rsqrtf(v2[oc] + BN_EPS);
        float bb  = be2[oc] + (b2[oc] - m2[oc]) * inv;
        #pragma unroll
        for (int mt = 0; mt < 2; ++mt)
            #pragma unroll
            for (int r = 0; r < 4; ++r) {
                int p = wm * 32 + mt * 16 + lo * 4 + r;
                u.pb.feat[oc][p] = fmaxf(cacc[mt][nt][r] * inv + bb, 0.f);
            }
    }
    __syncthreads();

    // ---- Haar cD ----
    #pragma unroll
    for (int r = 0; r < 4; ++r) {
        int idx = tid * 4 + r;             // 64c x 16yx
        int c = idx >> 4, yx = idx & 15;
        int y = yx >> 2, xx = yx & 3;
        float aa = u.pb.feat[c][(2 * y) * 8 + 2 * xx];
        float bb = u.pb.feat[c][(2 * y) * 8 + 2 * xx + 1];
        float cc = u.pb.feat[c][(2 * y + 1) * 8 + 2 * xx];
        float dd = u.pb.feat[c][(2 * y + 1) * 8 + 2 * xx + 1];
        u.pb.cd[c][yx] = 0.5f * (aa - bb - cc + dd);
    }
    __syncthreads();

    // ---- gating + attention logits ----
    const int q  = tid & 63;
    const int g  = wave;
    const int qy = q >> 3, qx = q & 7;
    const int qq = (qy >> 1) * 4 + (qx >> 1);
    float a2[16];
    float part = 0.f;
    #pragma unroll
    for (int j = 0; j < 16; ++j) {
        int oc = g * 16 + j;
        float v = u.pb.feat[oc][q] * u.pb.cd[oc][qq];
        a2[j] = v;
        part += v * wa[oc];
    }
    u.pb.attn[g][q] = part;
    __syncthreads();
    float s   = u.pb.attn[0][q] + u.pb.attn[1][q] + u.pb.attn[2][q] + u.pb.attn[3][q] + ba[0];
    float sig = 1.f / (1.f + __expf(-s));

    __bf16* fb = f + (size_t)b * 4096;
    #pragma unroll
    for (int j = 0; j < 16; ++j)
        fb[(g * 16 + j) * 64 + q] = (__bf16)(a2[j] * sig);
}

// ---------------- K3: dense1 GEMM: C[8192,512] = relu(A[8192,4096] @ B[512,4096]^T + bd1) ----------------
__global__ __launch_bounds__(256) void gemm1_kernel(
    const __bf16* __restrict__ A, const __bf16* __restrict__ B,
    const float* __restrict__ bias, __bf16* __restrict__ C)
{
    const int K = 4096, NOUT = 512;
    __shared__ __align__(16) __bf16 As[128][72];
    __shared__ __align__(16) __bf16 Bs[64][72];
    const int tid  = threadIdx.x;
    const int lane = tid & 63;
    const int wave = tid >> 6;
    const int wm = wave >> 1, wn = wave & 1;
    const int m0 = blockIdx.x * 128, n0 = blockIdx.y * 64;
    f32x4 acc[4][2] = {};
    for (int k0 = 0; k0 < K; k0 += 64) {
        #pragma unroll
        for (int r = 0; r < 4; ++r) {
            int i = r * 256 + tid;
            int row = i >> 3, gg = i & 7;
            *(bf16x8*)(&As[row][gg * 8]) = *(const bf16x8*)(A + (size_t)(m0 + row) * K + k0 + gg * 8);
        }
        #pragma unroll
        for (int r = 0; r < 2; ++r) {
            int i = r * 256 + tid;
            int row = i >> 3, gg = i & 7;
            *(bf16x8*)(&Bs[row][gg * 8]) = *(const bf16x8*)(B + (size_t)(n0 + row) * K + k0 + gg * 8);
        }
        __syncthreads();
        #pragma unroll
        for (int s = 0; s < 2; ++s) {
            int kk = s * 32 + (lane >> 4) * 8;
            bf16x8 af[4], bfr[2];
            #pragma unroll
            for (int mt = 0; mt < 4; ++mt)
                af[mt] = *(const bf16x8*)(&As[wm * 64 + mt * 16 + (lane & 15)][kk]);
            #pragma unroll
            for (int nt = 0; nt < 2; ++nt)
                bfr[nt] = *(const bf16x8*)(&Bs[wn * 32 + nt * 16 + (lane & 15)][kk]);
            #pragma unroll
            for (int mt = 0; mt < 4; ++mt)
                #pragma unroll
                for (int nt = 0; nt < 2; ++nt)
                    acc[mt][nt] = __builtin_amdgcn_mfma_f32_16x16x32_bf16(af[mt], bfr[nt], acc[mt][nt], 0, 0, 0);
        }
        __syncthreads();
    }
    #pragma unroll
    for (int mt = 0; mt < 4; ++mt)
        #pragma unroll
        for (int nt = 0; nt < 2; ++nt)
            #pragma unroll
            for (int r = 0; r < 4; ++r) {
                int m = m0 + wm * 64 + mt * 16 + (lane >> 4) * 4 + r;
                int n = n0 + wn * 32 + nt * 16 + (lane & 15);
                float v = acc[mt][nt][r] + bias[n];
                C[(size_t)m * NOUT + n] = (__bf16)fmaxf(v, 0.f);
            }
}

// ---------------- K4: dense2: out[8192,128] = sigmoid(A[8192,512] @ B[128,512]^T + bd2) ----------------
__global__ __launch_bounds__(256) void gemm2_kernel(
    const __bf16* __restrict__ A, const __bf16* __restrict__ B,
    const float* __restrict__ bias, float* __restrict__ Out)
{
    const int K = 512, NOUT = 128;
    __shared__ __align__(16) __bf16 As[64][72];
    __shared__ __align__(16) __bf16 Bs[128][72];
    const int tid  = threadIdx.x;
    const int lane = tid & 63;
    const int wave = tid >> 6;
    const int m0 = blockIdx.x * 64;
    f32x4 acc[4][2] = {};
    for (int k0 = 0; k0 < K; k0 += 64) {
        #pragma unroll
        for (int r = 0; r < 2; ++r) {
            int i = r * 256 + tid;
            int row = i >> 3, gg = i & 7;
            *(bf16x8*)(&As[row][gg * 8]) = *(const bf16x8*)(A + (size_t)(m0 + row) * K + k0 + gg * 8);
        }
        #pragma unroll
        for (int r = 0; r < 4; ++r) {
            int i = r * 256 + tid;
            int row = i >> 3, gg = i & 7;
            *(bf16x8*)(&Bs[row][gg * 8]) = *(const bf16x8*)(B + (size_t)row * K + k0 + gg * 8);
        }
        __syncthreads();
        #pragma unroll
        for (int s = 0; s < 2; ++s) {
            int kk = s * 32 + (lane >> 4) * 8;
            bf16x8 af[4], bfr[2];
            #pragma unroll
            for (int mt = 0; mt < 4; ++mt)
                af[mt] = *(const bf16x8*)(&As[mt * 16 + (lane & 15)][kk]);
            #pragma unroll
            for (int nt = 0; nt < 2; ++nt)
                bfr[nt] = *(const bf16x8*)(&Bs[wave * 32 + nt * 16 + (lane & 15)][kk]);
            #pragma unroll
            for (int mt = 0; mt < 4; ++mt)
                #pragma unroll
                for (int nt = 0; nt < 2; ++nt)
                    acc[mt][nt] = __builtin_amdgcn_mfma_f32_16x16x32_bf16(af[mt], bfr[nt], acc[mt][nt], 0, 0, 0);
        }
        __syncthreads();
    }
    #pragma unroll
    for (int mt = 0; mt < 4; ++mt)
        #pragma unroll
        for (int nt = 0; nt < 2; ++nt)
            #pragma unroll
            for (int r = 0; r < 4; ++r) {
                int m = m0 + mt * 16 + (lane >> 4) * 4 + r;
                int n = wave * 32 + nt * 16 + (lane & 15);
                float v = acc[mt][nt][r] + bias[n];
                Out[(size_t)m * NOUT + n] = 1.f / (1.f + __expf(-v));
            }
}

extern "C" void kernel_launch(void* const* d_in, const int* in_sizes, int n_in,
                              void* d_out, int out_size, void* d_ws, size_t ws_size,
                              hipStream_t stream)
{
    const float* x   = (const float*)d_in[0];
    const float* w1  = (const float*)d_in[1];
    const float* b1  = (const float*)d_in[2];
    const float* g1  = (const float*)d_in[3];
    const float* be1 = (const float*)d_in[4];
    const float* m1  = (const float*)d_in[5];
    const float* v1  = (const float*)d_in[6];
    const float* w2  = (const float*)d_in[7];
    const float* b2  = (const float*)d_in[8];
    const float* g2  = (const float*)d_in[9];
    const float* be2 = (const float*)d_in[10];
    const float* m2  = (const float*)d_in[11];
    const float* v2  = (const float*)d_in[12];
    const float* wa  = (const float*)d_in[13];
    const float* ba  = (const float*)d_in[14];
    const float* wd1 = (const float*)d_in[15];
    const float* bd1 = (const float*)d_in[16];
    const float* wd2 = (const float*)d_in[17];
    const float* bd2 = (const float*)d_in[18];

    char* ws = (char*)d_ws;
    __bf16* f_bf   = (__bf16*)(ws);                                   // 64 MiB
    __bf16* h1_bf  = (__bf16*)(ws + 67108864);                        //  8 MiB
    __bf16* wd1_bf = (__bf16*)(ws + 67108864 + 8388608);              //  4 MiB
    __bf16* wd2_bf = (__bf16*)(ws + 67108864 + 8388608 + 4194304);    // 128 KiB
    __bf16* w2r_bf = (__bf16*)(ws + 67108864 + 8388608 + 4194304 + 131072); // 36 KiB

    cvt_kernel<<<2048, 256, 0, stream>>>(wd1, wd1_bf, 512 * 4096);
    cvt_kernel<<<64, 256, 0, stream>>>(wd2, wd2_bf, 128 * 512);
    w2r_kernel<<<72, 256, 0, stream>>>(w2, w2r_bf);

    conv_fused_kernel<<<8192, 256, 0, stream>>>(x, w1, b1, g1, be1, m1, v1,
                                                w2r_bf, b2, g2, be2, m2, v2, wa, ba, f_bf);

    dim3 g3(64, 8);
    gemm1_kernel<<<g3, 256, 0, stream>>>(f_bf, wd1_bf, bd1, h1_bf);

    gemm2_kernel<<<128, 256, 0, stream>>>(h1_bf, wd2_bf, bd2, (float*)d_out);
}

// Round 3
// 332.995 us; speedup vs baseline: 2.6830x; 1.6762x over previous
//
#include <hip/hip_runtime.h>
#include <hip/hip_bf16.h>

typedef __bf16 bf16x8 __attribute__((ext_vector_type(8)));
typedef float f32x4 __attribute__((ext_vector_type(4)));

#define BN_EPS 1e-5f

// ---------------- K0: fp32 -> bf16 conversion ----------------
__global__ void cvt_kernel(const float* __restrict__ a, __bf16* __restrict__ o, int n) {
    int i = blockIdx.x * blockDim.x + threadIdx.x;
    int stride = gridDim.x * blockDim.x;
    for (; i < n; i += stride) o[i] = (__bf16)a[i];
}

// ---------------- K0a: reorder w1 [oc][ic][ky][kx] -> [oc][o=(ic*5+ky)][kx pad 8] bf16, K=128 ----------------
__global__ void w1r_kernel(const float* __restrict__ w1, __bf16* __restrict__ o) {
    int i = blockIdx.x * 256 + threadIdx.x;   // 32*128 = 4096
    if (i < 4096) {
        int oc = i >> 7, rem = i & 127;
        int ot = rem >> 3, j = rem & 7;
        float v = 0.f;
        if (ot < 15 && j < 5) {
            int ic = ot / 5, ky = ot % 5;
            v = w1[((oc * 3 + ic) * 5 + ky) * 5 + j];
        }
        o[i] = (__bf16)v;
    }
}

// ---------------- K0b: reorder w2 [oc][ic][tap] -> [oc][tap][ic] bf16 ----------------
__global__ void w2r_kernel(const float* __restrict__ w2, __bf16* __restrict__ o) {
    int i = blockIdx.x * 256 + threadIdx.x;
    if (i < 64 * 288) {
        int oc = i / 288, rem = i % 288;
        int tap = rem / 32, ic = rem % 32;
        o[i] = (__bf16)w2[(oc * 32 + ic) * 9 + tap];
    }
}

// ---------------- K12: fused conv1(MFMA)+bn+relu + conv2(MFMA)+bn+relu + haar+attn -> f ----------------
// one block per image, 256 threads = 4 waves. LDS 40400 B -> 4 blocks/CU.
__global__ __launch_bounds__(256, 4) void conv_fused_kernel(
    const float* __restrict__ x,
    const __bf16* __restrict__ w1r, const float* __restrict__ b1,
    const float* __restrict__ g1, const float* __restrict__ be1,
    const float* __restrict__ m1, const float* __restrict__ v1,
    const __bf16* __restrict__ w2r, const float* __restrict__ b2,
    const float* __restrict__ g2, const float* __restrict__ be2,
    const float* __restrict__ m2, const float* __restrict__ v2,
    const float* __restrict__ wa, const float* __restrict__ ba,
    __bf16* __restrict__ f)
{
    // UA: conv1 input (fp32, zero-padded) unions with feat (conv2 output)
    union UA { float xs[3][36][40]; float feat[64][64]; };
    // UB: conv1 output hs (channel-last bf16, pixel stride 40 for bank stagger)
    //     unions with cd + attn scratch
    struct PB { float cd[64][16]; float attn[4][64]; };
    union UB { __bf16 hs[289 * 40]; PB pb; };
    __shared__ __align__(16) UA ua;   // 17280 B
    __shared__ __align__(16) UB ub;   // 23120 B

    const int b    = blockIdx.x;
    const int tid  = threadIdx.x;
    const int lane = tid & 63;
    const int wave = tid >> 6;
    const int lo   = lane >> 4;      // k-octet index within a 32-k step / C row group
    const int ln   = lane & 15;      // MFMA m/n index

    float* xsf = &ua.xs[0][0][0];
    __bf16* hsf = ub.hs;

    // ---- phase 0: zero xs (all 4320 floats) + hs border (row 0, col 0: 33 pixels x 32ch) ----
    {
        float4* xp = (float4*)xsf;
        for (int i = tid; i < 1080; i += 256) xp[i] = float4{0.f, 0.f, 0.f, 0.f};
        if (tid < 132) {
            int pi = tid >> 2, ch = tid & 3;
            int pix = (pi < 17) ? pi : (pi - 16) * 17;
            bf16x8 z = {};
            *(bf16x8*)&hsf[pix * 40 + ch * 8] = z;
        }
    }
    __syncthreads();

    // ---- phase 1: stage x: logical x[ic][iy][ix] -> xs[ic][iy+2][ix+4] (16B aligned) ----
    {
        const float4* xb = (const float4*)(x + (size_t)b * 3072);
        #pragma unroll
        for (int r = 0; r < 3; ++r) {
            int c = r * 256 + tid;              // 0..767
            int plane = c >> 8, rem = c & 255;
            int row = rem >> 3, c4 = rem & 7;
            *(float4*)&ua.xs[plane][row + 2][4 + c4 * 4] = xb[c];
        }
    }

    // preload conv1 B fragments: w1r[oc=nt*16+ln][octet = s*4+lo][8]
    bf16x8 bw1[2][4];
    #pragma unroll
    for (int nt = 0; nt < 2; ++nt)
        #pragma unroll
        for (int s = 0; s < 4; ++s)
            bw1[nt][s] = *(const bf16x8*)(w1r + (nt * 16 + ln) * 128 + (s * 4 + lo) * 8);
    __syncthreads();

    // ---- phase 2: conv1 5x5 s2 p2 as MFMA. M=16 pixels/row-tile (ox=ln), N=32 oc, K=128 ----
    // wave handles 4 output rows: oy = wave*4 + mt
    f32x4 c1[4][2] = {};
    #pragma unroll
    for (int s = 0; s < 4; ++s) {
        const int o  = s * 4 + lo;                 // octet = (ic,ky), o=15 -> dummy zero
        const int ic = (o * 205) >> 10;            // o/5  (o=15 -> 3)
        const int ky = o - ic * 5;
        const bool dummy = (o == 15);
        const int icc = dummy ? 2 : ic;
        // col base: input col ix = 2*ox + kx - 2 stored at ix+4 -> col = 2*ox + kx + 2
        const int cbase = icc * 1440 + 2 * ln + 2;
        #pragma unroll
        for (int mt = 0; mt < 4; ++mt) {
            const int oy  = wave * 4 + mt;
            const int row = dummy ? 35 : (2 * oy + ky);   // row 35 of plane 2 is always zero
            const int idx = cbase + row * 40;
            float2 p0 = *(const float2*)&xsf[idx];
            float2 p1 = *(const float2*)&xsf[idx + 2];
            float  p2 = xsf[idx + 4];
            bf16x8 af;
            af[0] = (__bf16)p0.x; af[1] = (__bf16)p0.y;
            af[2] = (__bf16)p1.x; af[3] = (__bf16)p1.y;
            af[4] = (__bf16)p2;
            af[5] = (__bf16)0.f; af[6] = (__bf16)0.f; af[7] = (__bf16)0.f;
            #pragma unroll
            for (int nt = 0; nt < 2; ++nt)
                c1[mt][nt] = __builtin_amdgcn_mfma_f32_16x16x32_bf16(af, bw1[nt][s], c1[mt][nt], 0, 0, 0);
        }
    }

    // ---- BN1 + ReLU -> hs (channel-last). C layout: m=ox=lo*4+r, n=oc=nt*16+ln ----
    #pragma unroll
    for (int nt = 0; nt < 2; ++nt) {
        const int oc  = nt * 16 + ln;
        const float inv = g1[oc] * rsqrtf(v1[oc] + BN_EPS);
        const float bb  = be1[oc] + (b1[oc] - m1[oc]) * inv;
        #pragma unroll
        for (int mt = 0; mt < 4; ++mt) {
            const int hy = wave * 4 + mt + 1;
            #pragma unroll
            for (int r = 0; r < 4; ++r) {
                const int hx = lo * 4 + r + 1;
                hsf[(hy * 17 + hx) * 40 + oc] = (__bf16)fmaxf(c1[mt][nt][r] * inv + bb, 0.f);
            }
        }
    }

    // preload conv2 B fragments (after conv1 regs die -> keeps VGPR < 128)
    const int wm = wave >> 1, wn = wave & 1;
    bf16x8 bw2[2][9];
    #pragma unroll
    for (int nt = 0; nt < 2; ++nt) {
        const __bf16* wp = w2r + (wn * 32 + nt * 16 + ln) * 288 + lo * 8;
        #pragma unroll
        for (int ks = 0; ks < 9; ++ks)
            bw2[nt][ks] = *(const bf16x8*)(wp + ks * 32);
    }
    __syncthreads();

    // ---- phase 3: conv2 3x3 s2 p1 as MFMA: M=64 pix, N=64 oc, K=288 (tap-major, ic fast) ----
    f32x4 c2[2][2] = {};
    {
        int pixbase[2];
        #pragma unroll
        for (int mt = 0; mt < 2; ++mt) {
            int p = wm * 32 + mt * 16 + ln;
            int qy = p >> 3, qx = p & 7;
            pixbase[mt] = (2 * qy * 17 + 2 * qx) * 40 + lo * 8;
        }
        #pragma unroll
        for (int ks = 0; ks < 9; ++ks) {
            const int ty = ks / 3, tx = ks % 3;
            bf16x8 af[2];
            #pragma unroll
            for (int mt = 0; mt < 2; ++mt)
                af[mt] = *(const bf16x8*)&hsf[pixbase[mt] + (ty * 17 + tx) * 40];
            #pragma unroll
            for (int mt = 0; mt < 2; ++mt)
                #pragma unroll
                for (int nt = 0; nt < 2; ++nt)
                    c2[mt][nt] = __builtin_amdgcn_mfma_f32_16x16x32_bf16(af[mt], bw2[nt][ks], c2[mt][nt], 0, 0, 0);
        }
    }

    // ---- BN2 + ReLU -> feat[oc][pixel] (into UA; xs reads all done) ----
    #pragma unroll
    for (int nt = 0; nt < 2; ++nt) {
        const int oc  = wn * 32 + nt * 16 + ln;
        const float inv = g2[oc] * rsqrtf(v2[oc] + BN_EPS);
        const float bb  = be2[oc] + (b2[oc] - m2[oc]) * inv;
        #pragma unroll
        for (int mt = 0; mt < 2; ++mt)
            #pragma unroll
            for (int r = 0; r < 4; ++r) {
                const int p = wm * 32 + mt * 16 + lo * 4 + r;
                ua.feat[oc][p] = fmaxf(c2[mt][nt][r] * inv + bb, 0.f);
            }
    }
    __syncthreads();

    // ---- phase 4: Haar cD (into UB; hs reads all done) ----
    #pragma unroll
    for (int r = 0; r < 4; ++r) {
        int idx = tid * 4 + r;             // 64c x 16yx
        int c = idx >> 4, yx = idx & 15;
        int y = yx >> 2, xx = yx & 3;
        float aa = ua.feat[c][(2 * y) * 8 + 2 * xx];
        float bb = ua.feat[c][(2 * y) * 8 + 2 * xx + 1];
        float cc = ua.feat[c][(2 * y + 1) * 8 + 2 * xx];
        float dd = ua.feat[c][(2 * y + 1) * 8 + 2 * xx + 1];
        ub.pb.cd[c][yx] = 0.5f * (aa - bb - cc + dd);
    }
    __syncthreads();

    // ---- phase 5: gating + attention ----
    const int q  = tid & 63;
    const int g  = wave;
    const int qy = q >> 3, qx = q & 7;
    const int qq = (qy >> 1) * 4 + (qx >> 1);
    float a2[16];
    float part = 0.f;
    #pragma unroll
    for (int j = 0; j < 16; ++j) {
        int oc = g * 16 + j;
        float v = ua.feat[oc][q] * ub.pb.cd[oc][qq];
        a2[j] = v;
        part += v * wa[oc];
    }
    ub.pb.attn[g][q] = part;
    __syncthreads();
    float s2  = ub.pb.attn[0][q] + ub.pb.attn[1][q] + ub.pb.attn[2][q] + ub.pb.attn[3][q] + ba[0];
    float sig = 1.f / (1.f + __expf(-s2));

    __bf16* fb = f + (size_t)b * 4096;
    #pragma unroll
    for (int j = 0; j < 16; ++j)
        fb[(g * 16 + j) * 64 + q] = (__bf16)(a2[j] * sig);
}

// ---------------- K3: dense1 GEMM: C[8192,512] = relu(A[8192,4096] @ B[512,4096]^T + bd1) ----------------
__global__ __launch_bounds__(256) void gemm1_kernel(
    const __bf16* __restrict__ A, const __bf16* __restrict__ B,
    const float* __restrict__ bias, __bf16* __restrict__ C)
{
    const int K = 4096, NOUT = 512;
    __shared__ __align__(16) __bf16 As[128][72];
    __shared__ __align__(16) __bf16 Bs[64][72];
    const int tid  = threadIdx.x;
    const int lane = tid & 63;
    const int wave = tid >> 6;
    const int wm = wave >> 1, wn = wave & 1;
    const int m0 = blockIdx.x * 128, n0 = blockIdx.y * 64;
    f32x4 acc[4][2] = {};
    for (int k0 = 0; k0 < K; k0 += 64) {
        #pragma unroll
        for (int r = 0; r < 4; ++r) {
            int i = r * 256 + tid;
            int row = i >> 3, gg = i & 7;
            *(bf16x8*)(&As[row][gg * 8]) = *(const bf16x8*)(A + (size_t)(m0 + row) * K + k0 + gg * 8);
        }
        #pragma unroll
        for (int r = 0; r < 2; ++r) {
            int i = r * 256 + tid;
            int row = i >> 3, gg = i & 7;
            *(bf16x8*)(&Bs[row][gg * 8]) = *(const bf16x8*)(B + (size_t)(n0 + row) * K + k0 + gg * 8);
        }
        __syncthreads();
        #pragma unroll
        for (int s = 0; s < 2; ++s) {
            int kk = s * 32 + (lane >> 4) * 8;
            bf16x8 af[4], bfr[2];
            #pragma unroll
            for (int mt = 0; mt < 4; ++mt)
                af[mt] = *(const bf16x8*)(&As[wm * 64 + mt * 16 + (lane & 15)][kk]);
            #pragma unroll
            for (int nt = 0; nt < 2; ++nt)
                bfr[nt] = *(const bf16x8*)(&Bs[wn * 32 + nt * 16 + (lane & 15)][kk]);
            #pragma unroll
            for (int mt = 0; mt < 4; ++mt)
                #pragma unroll
                for (int nt = 0; nt < 2; ++nt)
                    acc[mt][nt] = __builtin_amdgcn_mfma_f32_16x16x32_bf16(af[mt], bfr[nt], acc[mt][nt], 0, 0, 0);
        }
        __syncthreads();
    }
    #pragma unroll
    for (int mt = 0; mt < 4; ++mt)
        #pragma unroll
        for (int nt = 0; nt < 2; ++nt)
            #pragma unroll
            for (int r = 0; r < 4; ++r) {
                int m = m0 + wm * 64 + mt * 16 + (lane >> 4) * 4 + r;
                int n = n0 + wn * 32 + nt * 16 + (lane & 15);
                float v = acc[mt][nt][r] + bias[n];
                C[(size_t)m * NOUT + n] = (__bf16)fmaxf(v, 0.f);
            }
}

// ---------------- K4: dense2: out[8192,128] = sigmoid(A[8192,512] @ B[128,512]^T + bd2) ----------------
__global__ __launch_bounds__(256) void gemm2_kernel(
    const __bf16* __restrict__ A, const __bf16* __restrict__ B,
    const float* __restrict__ bias, float* __restrict__ Out)
{
    const int K = 512, NOUT = 128;
    __shared__ __align__(16) __bf16 As[64][72];
    __shared__ __align__(16) __bf16 Bs[128][72];
    const int tid  = threadIdx.x;
    const int lane = tid & 63;
    const int wave = tid >> 6;
    const int m0 = blockIdx.x * 64;
    f32x4 acc[4][2] = {};
    for (int k0 = 0; k0 < K; k0 += 64) {
        #pragma unroll
        for (int r = 0; r < 2; ++r) {
            int i = r * 256 + tid;
            int row = i >> 3, gg = i & 7;
            *(bf16x8*)(&As[row][gg * 8]) = *(const bf16x8*)(A + (size_t)(m0 + row) * K + k0 + gg * 8);
        }
        #pragma unroll
        for (int r = 0; r < 4; ++r) {
            int i = r * 256 + tid;
            int row = i >> 3, gg = i & 7;
            *(bf16x8*)(&Bs[row][gg * 8]) = *(const bf16x8*)(B + (size_t)row * K + k0 + gg * 8);
        }
        __syncthreads();
        #pragma unroll
        for (int s = 0; s < 2; ++s) {
            int kk = s * 32 + (lane >> 4) * 8;
            bf16x8 af[4], bfr[2];
            #pragma unroll
            for (int mt = 0; mt < 4; ++mt)
                af[mt] = *(const bf16x8*)(&As[mt * 16 + (lane & 15)][kk]);
            #pragma unroll
            for (int nt = 0; nt < 2; ++nt)
                bfr[nt] = *(const bf16x8*)(&Bs[wave * 32 + nt * 16 + (lane & 15)][kk]);
            #pragma unroll
            for (int mt = 0; mt < 4; ++mt)
                #pragma unroll
                for (int nt = 0; nt < 2; ++nt)
                    acc[mt][nt] = __builtin_amdgcn_mfma_f32_16x16x32_bf16(af[mt], bfr[nt], acc[mt][nt], 0, 0, 0);
        }
        __syncthreads();
    }
    #pragma unroll
    for (int mt = 0; mt < 4; ++mt)
        #pragma unroll
        for (int nt = 0; nt < 2; ++nt)
            #pragma unroll
            for (int r = 0; r < 4; ++r) {
                int m = m0 + mt * 16 + (lane >> 4) * 4 + r;
                int n = wave * 32 + nt * 16 + (lane & 15);
                float v = acc[mt][nt][r] + bias[n];
                Out[(size_t)m * NOUT + n] = 1.f / (1.f + __expf(-v));
            }
}

extern "C" void kernel_launch(void* const* d_in, const int* in_sizes, int n_in,
                              void* d_out, int out_size, void* d_ws, size_t ws_size,
                              hipStream_t stream)
{
    const float* x   = (const float*)d_in[0];
    const float* w1  = (const float*)d_in[1];
    const float* b1  = (const float*)d_in[2];
    const float* g1  = (const float*)d_in[3];
    const float* be1 = (const float*)d_in[4];
    const float* m1  = (const float*)d_in[5];
    const float* v1  = (const float*)d_in[6];
    const float* w2  = (const float*)d_in[7];
    const float* b2  = (const float*)d_in[8];
    const float* g2  = (const float*)d_in[9];
    const float* be2 = (const float*)d_in[10];
    const float* m2  = (const float*)d_in[11];
    const float* v2  = (const float*)d_in[12];
    const float* wa  = (const float*)d_in[13];
    const float* ba  = (const float*)d_in[14];
    const float* wd1 = (const float*)d_in[15];
    const float* bd1 = (const float*)d_in[16];
    const float* wd2 = (const float*)d_in[17];
    const float* bd2 = (const float*)d_in[18];

    char* ws = (char*)d_ws;
    __bf16* f_bf   = (__bf16*)(ws);                                       // 64 MiB
    __bf16* h1_bf  = (__bf16*)(ws + 67108864);                            //  8 MiB
    __bf16* wd1_bf = (__bf16*)(ws + 67108864 + 8388608);                  //  4 MiB
    __bf16* wd2_bf = (__bf16*)(ws + 67108864 + 8388608 + 4194304);        // 128 KiB
    __bf16* w2r_bf = (__bf16*)(ws + 67108864 + 8388608 + 4194304 + 131072);     // 64 KiB slot
    __bf16* w1r_bf = (__bf16*)(ws + 67108864 + 8388608 + 4194304 + 131072 + 65536); // 8 KiB

    cvt_kernel<<<2048, 256, 0, stream>>>(wd1, wd1_bf, 512 * 4096);
    cvt_kernel<<<64, 256, 0, stream>>>(wd2, wd2_bf, 128 * 512);
    w1r_kernel<<<16, 256, 0, stream>>>(w1, w1r_bf);
    w2r_kernel<<<72, 256, 0, stream>>>(w2, w2r_bf);

    conv_fused_kernel<<<8192, 256, 0, stream>>>(x, w1r_bf, b1, g1, be1, m1, v1,
                                                w2r_bf, b2, g2, be2, m2, v2, wa, ba, f_bf);

    dim3 g3(64, 8);
    gemm1_kernel<<<g3, 256, 0, stream>>>(f_bf, wd1_bf, bd1, h1_bf);

    gemm2_kernel<<<128, 256, 0, stream>>>(h1_bf, wd2_bf, bd2, (float*)d_out);
}

// Round 4
// 317.215 us; speedup vs baseline: 2.8165x; 1.0497x over previous
//
#include <hip/hip_runtime.h>
#include <hip/hip_bf16.h>

typedef __bf16 bf16x8 __attribute__((ext_vector_type(8)));
typedef float f32x4 __attribute__((ext_vector_type(4)));

#define BN_EPS 1e-5f

// async global->LDS 16B DMA. LDS dest must be wave-uniform base + lane*16.
__device__ __forceinline__ void gl_lds16(const __bf16* g, __bf16* l) {
    __builtin_amdgcn_global_load_lds(
        (const __attribute__((address_space(1))) unsigned int*)g,
        (__attribute__((address_space(3))) unsigned int*)l,
        16, 0, 0);
}

// ---------------- K0: fp32 -> bf16 conversion ----------------
__global__ void cvt_kernel(const float* __restrict__ a, __bf16* __restrict__ o, int n) {
    int i = blockIdx.x * blockDim.x + threadIdx.x;
    int stride = gridDim.x * blockDim.x;
    for (; i < n; i += stride) o[i] = (__bf16)a[i];
}

// ---------------- K0a: reorder w1 [oc][ic][ky][kx] -> [oc][o=(ic*5+ky)][kx pad 8] bf16, K=128 ----------------
__global__ void w1r_kernel(const float* __restrict__ w1, __bf16* __restrict__ o) {
    int i = blockIdx.x * 256 + threadIdx.x;   // 32*128 = 4096
    if (i < 4096) {
        int oc = i >> 7, rem = i & 127;
        int ot = rem >> 3, j = rem & 7;
        float v = 0.f;
        if (ot < 15 && j < 5) {
            int ic = ot / 5, ky = ot % 5;
            v = w1[((oc * 3 + ic) * 5 + ky) * 5 + j];
        }
        o[i] = (__bf16)v;
    }
}

// ---------------- K0b: reorder w2 [oc][ic][tap] -> [oc][tap][ic] bf16 ----------------
__global__ void w2r_kernel(const float* __restrict__ w2, __bf16* __restrict__ o) {
    int i = blockIdx.x * 256 + threadIdx.x;
    if (i < 64 * 288) {
        int oc = i / 288, rem = i % 288;
        int tap = rem / 32, ic = rem % 32;
        o[i] = (__bf16)w2[(oc * 32 + ic) * 9 + tap];
    }
}

// ---------------- K12: fused conv1(MFMA)+bn+relu + conv2(MFMA)+bn+relu + haar+attn -> f ----------------
// one block per image, 256 threads = 4 waves. LDS 40400 B -> 4 blocks/CU.
__global__ __launch_bounds__(256, 4) void conv_fused_kernel(
    const float* __restrict__ x,
    const __bf16* __restrict__ w1r, const float* __restrict__ b1,
    const float* __restrict__ g1, const float* __restrict__ be1,
    const float* __restrict__ m1, const float* __restrict__ v1,
    const __bf16* __restrict__ w2r, const float* __restrict__ b2,
    const float* __restrict__ g2, const float* __restrict__ be2,
    const float* __restrict__ m2, const float* __restrict__ v2,
    const float* __restrict__ wa, const float* __restrict__ ba,
    __bf16* __restrict__ f)
{
    union UA { float xs[3][36][40]; float feat[64][64]; };
    struct PB { float cd[64][16]; float attn[4][64]; };
    union UB { __bf16 hs[289 * 40]; PB pb; };
    __shared__ __align__(16) UA ua;   // 17280 B
    __shared__ __align__(16) UB ub;   // 23120 B

    const int b    = blockIdx.x;
    const int tid  = threadIdx.x;
    const int lane = tid & 63;
    const int wave = tid >> 6;
    const int lo   = lane >> 4;
    const int ln   = lane & 15;

    float* xsf = &ua.xs[0][0][0];
    __bf16* hsf = ub.hs;

    // ---- phase 0: zero xs + hs border ----
    {
        float4* xp = (float4*)xsf;
        for (int i = tid; i < 1080; i += 256) xp[i] = float4{0.f, 0.f, 0.f, 0.f};
        if (tid < 132) {
            int pi = tid >> 2, ch = tid & 3;
            int pix = (pi < 17) ? pi : (pi - 16) * 17;
            bf16x8 z = {};
            *(bf16x8*)&hsf[pix * 40 + ch * 8] = z;
        }
    }
    __syncthreads();

    // ---- phase 1: stage x: x[ic][iy][ix] -> xs[ic][iy+2][ix+4] ----
    {
        const float4* xb = (const float4*)(x + (size_t)b * 3072);
        #pragma unroll
        for (int r = 0; r < 3; ++r) {
            int c = r * 256 + tid;
            int plane = c >> 8, rem = c & 255;
            int row = rem >> 3, c4 = rem & 7;
            *(float4*)&ua.xs[plane][row + 2][4 + c4 * 4] = xb[c];
        }
    }

    bf16x8 bw1[2][4];
    #pragma unroll
    for (int nt = 0; nt < 2; ++nt)
        #pragma unroll
        for (int s = 0; s < 4; ++s)
            bw1[nt][s] = *(const bf16x8*)(w1r + (nt * 16 + ln) * 128 + (s * 4 + lo) * 8);
    __syncthreads();

    // ---- phase 2: conv1 5x5 s2 p2 as MFMA ----
    f32x4 c1[4][2] = {};
    #pragma unroll
    for (int s = 0; s < 4; ++s) {
        const int o  = s * 4 + lo;
        const int ic = (o * 205) >> 10;
        const int ky = o - ic * 5;
        const bool dummy = (o == 15);
        const int icc = dummy ? 2 : ic;
        const int cbase = icc * 1440 + 2 * ln + 2;
        #pragma unroll
        for (int mt = 0; mt < 4; ++mt) {
            const int oy  = wave * 4 + mt;
            const int row = dummy ? 35 : (2 * oy + ky);
            const int idx = cbase + row * 40;
            float2 p0 = *(const float2*)&xsf[idx];
            float2 p1 = *(const float2*)&xsf[idx + 2];
            float  p2 = xsf[idx + 4];
            bf16x8 af;
            af[0] = (__bf16)p0.x; af[1] = (__bf16)p0.y;
            af[2] = (__bf16)p1.x; af[3] = (__bf16)p1.y;
            af[4] = (__bf16)p2;
            af[5] = (__bf16)0.f; af[6] = (__bf16)0.f; af[7] = (__bf16)0.f;
            #pragma unroll
            for (int nt = 0; nt < 2; ++nt)
                c1[mt][nt] = __builtin_amdgcn_mfma_f32_16x16x32_bf16(af, bw1[nt][s], c1[mt][nt], 0, 0, 0);
        }
    }

    // ---- BN1 + ReLU -> hs ----
    #pragma unroll
    for (int nt = 0; nt < 2; ++nt) {
        const int oc  = nt * 16 + ln;
        const float inv = g1[oc] * rsqrtf(v1[oc] + BN_EPS);
        const float bb  = be1[oc] + (b1[oc] - m1[oc]) * inv;
        #pragma unroll
        for (int mt = 0; mt < 4; ++mt) {
            const int hy = wave * 4 + mt + 1;
            #pragma unroll
            for (int r = 0; r < 4; ++r) {
                const int hx = lo * 4 + r + 1;
                hsf[(hy * 17 + hx) * 40 + oc] = (__bf16)fmaxf(c1[mt][nt][r] * inv + bb, 0.f);
            }
        }
    }

    const int wm = wave >> 1, wn = wave & 1;
    bf16x8 bw2[2][9];
    #pragma unroll
    for (int nt = 0; nt < 2; ++nt) {
        const __bf16* wp = w2r + (wn * 32 + nt * 16 + ln) * 288 + lo * 8;
        #pragma unroll
        for (int ks = 0; ks < 9; ++ks)
            bw2[nt][ks] = *(const bf16x8*)(wp + ks * 32);
    }
    __syncthreads();

    // ---- phase 3: conv2 3x3 s2 p1 as MFMA ----
    f32x4 c2[2][2] = {};
    {
        int pixbase[2];
        #pragma unroll
        for (int mt = 0; mt < 2; ++mt) {
            int p = wm * 32 + mt * 16 + ln;
            int qy = p >> 3, qx = p & 7;
            pixbase[mt] = (2 * qy * 17 + 2 * qx) * 40 + lo * 8;
        }
        #pragma unroll
        for (int ks = 0; ks < 9; ++ks) {
            const int ty = ks / 3, tx = ks % 3;
            bf16x8 af[2];
            #pragma unroll
            for (int mt = 0; mt < 2; ++mt)
                af[mt] = *(const bf16x8*)&hsf[pixbase[mt] + (ty * 17 + tx) * 40];
            #pragma unroll
            for (int mt = 0; mt < 2; ++mt)
                #pragma unroll
                for (int nt = 0; nt < 2; ++nt)
                    c2[mt][nt] = __builtin_amdgcn_mfma_f32_16x16x32_bf16(af[mt], bw2[nt][ks], c2[mt][nt], 0, 0, 0);
        }
    }

    // ---- BN2 + ReLU -> feat ----
    #pragma unroll
    for (int nt = 0; nt < 2; ++nt) {
        const int oc  = wn * 32 + nt * 16 + ln;
        const float inv = g2[oc] * rsqrtf(v2[oc] + BN_EPS);
        const float bb  = be2[oc] + (b2[oc] - m2[oc]) * inv;
        #pragma unroll
        for (int mt = 0; mt < 2; ++mt)
            #pragma unroll
            for (int r = 0; r < 4; ++r) {
                const int p = wm * 32 + mt * 16 + lo * 4 + r;
                ua.feat[oc][p] = fmaxf(c2[mt][nt][r] * inv + bb, 0.f);
            }
    }
    __syncthreads();

    // ---- phase 4: Haar cD ----
    #pragma unroll
    for (int r = 0; r < 4; ++r) {
        int idx = tid * 4 + r;
        int c = idx >> 4, yx = idx & 15;
        int y = yx >> 2, xx = yx & 3;
        float aa = ua.feat[c][(2 * y) * 8 + 2 * xx];
        float bb = ua.feat[c][(2 * y) * 8 + 2 * xx + 1];
        float cc = ua.feat[c][(2 * y + 1) * 8 + 2 * xx];
        float dd = ua.feat[c][(2 * y + 1) * 8 + 2 * xx + 1];
        ub.pb.cd[c][yx] = 0.5f * (aa - bb - cc + dd);
    }
    __syncthreads();

    // ---- phase 5: gating + attention ----
    const int q  = tid & 63;
    const int g  = wave;
    const int qy = q >> 3, qx = q & 7;
    const int qq = (qy >> 1) * 4 + (qx >> 1);
    float a2[16];
    float part = 0.f;
    #pragma unroll
    for (int j = 0; j < 16; ++j) {
        int oc = g * 16 + j;
        float v = ua.feat[oc][q] * ub.pb.cd[oc][qq];
        a2[j] = v;
        part += v * wa[oc];
    }
    ub.pb.attn[g][q] = part;
    __syncthreads();
    float s2  = ub.pb.attn[0][q] + ub.pb.attn[1][q] + ub.pb.attn[2][q] + ub.pb.attn[3][q] + ba[0];
    float sig = 1.f / (1.f + __expf(-s2));

    __bf16* fb = f + (size_t)b * 4096;
    #pragma unroll
    for (int j = 0; j < 16; ++j)
        fb[(g * 16 + j) * 64 + q] = (__bf16)(a2[j] * sig);
}

// ---------------- K3: dense1 GEMM: C[8192,512] = relu(A[8192,4096] @ B[512,4096]^T + bd1) ----------------
// 128x64 tile, BK=64, global_load_lds staging, XOR-swizzled unpadded LDS.
__global__ __launch_bounds__(256) void gemm1_kernel(
    const __bf16* __restrict__ A, const __bf16* __restrict__ B,
    const float* __restrict__ bias, __bf16* __restrict__ C)
{
    const int K = 4096, NOUT = 512;
    __shared__ __align__(16) __bf16 As[128][64];
    __shared__ __align__(16) __bf16 Bs[64][64];
    const int tid  = threadIdx.x;
    const int lane = tid & 63;
    const int wave = tid >> 6;
    const int wm = wave >> 1, wn = wave & 1;
    const int lo = lane >> 4, ln = lane & 15;
    const int m0 = blockIdx.x * 128, n0 = blockIdx.y * 64;
    const int sw = ln & 7;
    f32x4 acc[4][2] = {};
    for (int k0 = 0; k0 < K; k0 += 64) {
        // A: 128 rows x 8 chunks = 1024 chunks; slot cs holds global chunk cs^(row&7)
        #pragma unroll
        for (int r = 0; r < 4; ++r) {
            int i = r * 256 + tid;
            int row = i >> 3, cs = i & 7;
            gl_lds16(A + (size_t)(m0 + row) * K + k0 + (cs ^ (row & 7)) * 8,
                     &As[0][0] + i * 8);
        }
        #pragma unroll
        for (int r = 0; r < 2; ++r) {
            int i = r * 256 + tid;
            int row = i >> 3, cs = i & 7;
            gl_lds16(B + (size_t)(n0 + row) * K + k0 + (cs ^ (row & 7)) * 8,
                     &Bs[0][0] + i * 8);
        }
        __syncthreads();
        #pragma unroll
        for (int s = 0; s < 2; ++s) {
            const int c = s * 4 + lo;            // logical chunk, k = c*8..c*8+7
            const int slot = (c ^ sw) * 8;
            bf16x8 af[4], bfr[2];
            #pragma unroll
            for (int mt = 0; mt < 4; ++mt)
                af[mt] = *(const bf16x8*)(&As[wm * 64 + mt * 16 + ln][slot]);
            #pragma unroll
            for (int nt = 0; nt < 2; ++nt)
                bfr[nt] = *(const bf16x8*)(&Bs[wn * 32 + nt * 16 + ln][slot]);
            #pragma unroll
            for (int mt = 0; mt < 4; ++mt)
                #pragma unroll
                for (int nt = 0; nt < 2; ++nt)
                    acc[mt][nt] = __builtin_amdgcn_mfma_f32_16x16x32_bf16(af[mt], bfr[nt], acc[mt][nt], 0, 0, 0);
        }
        __syncthreads();
    }
    #pragma unroll
    for (int mt = 0; mt < 4; ++mt)
        #pragma unroll
        for (int nt = 0; nt < 2; ++nt)
            #pragma unroll
            for (int r = 0; r < 4; ++r) {
                int m = m0 + wm * 64 + mt * 16 + lo * 4 + r;
                int n = n0 + wn * 32 + nt * 16 + ln;
                float v = acc[mt][nt][r] + bias[n];
                C[(size_t)m * NOUT + n] = (__bf16)fmaxf(v, 0.f);
            }
}

// ---------------- K4: dense2: out[8192,128] = sigmoid(A[8192,512] @ B[128,512]^T + bd2) ----------------
__global__ __launch_bounds__(256) void gemm2_kernel(
    const __bf16* __restrict__ A, const __bf16* __restrict__ B,
    const float* __restrict__ bias, float* __restrict__ Out)
{
    const int K = 512, NOUT = 128;
    __shared__ __align__(16) __bf16 As[64][64];
    __shared__ __align__(16) __bf16 Bs[128][64];
    const int tid  = threadIdx.x;
    const int lane = tid & 63;
    const int wave = tid >> 6;
    const int lo = lane >> 4, ln = lane & 15;
    const int m0 = blockIdx.x * 64;
    const int sw = ln & 7;
    f32x4 acc[4][2] = {};
    for (int k0 = 0; k0 < K; k0 += 64) {
        #pragma unroll
        for (int r = 0; r < 2; ++r) {
            int i = r * 256 + tid;
            int row = i >> 3, cs = i & 7;
            gl_lds16(A + (size_t)(m0 + row) * K + k0 + (cs ^ (row & 7)) * 8,
                     &As[0][0] + i * 8);
        }
        #pragma unroll
        for (int r = 0; r < 4; ++r) {
            int i = r * 256 + tid;
            int row = i >> 3, cs = i & 7;
            gl_lds16(B + (size_t)row * K + k0 + (cs ^ (row & 7)) * 8,
                     &Bs[0][0] + i * 8);
        }
        __syncthreads();
        #pragma unroll
        for (int s = 0; s < 2; ++s) {
            const int c = s * 4 + lo;
            const int slot = (c ^ sw) * 8;
            bf16x8 af[4], bfr[2];
            #pragma unroll
            for (int mt = 0; mt < 4; ++mt)
                af[mt] = *(const bf16x8*)(&As[mt * 16 + ln][slot]);
            #pragma unroll
            for (int nt = 0; nt < 2; ++nt)
                bfr[nt] = *(const bf16x8*)(&Bs[wave * 32 + nt * 16 + ln][slot]);
            #pragma unroll
            for (int mt = 0; mt < 4; ++mt)
                #pragma unroll
                for (int nt = 0; nt < 2; ++nt)
                    acc[mt][nt] = __builtin_amdgcn_mfma_f32_16x16x32_bf16(af[mt], bfr[nt], acc[mt][nt], 0, 0, 0);
        }
        __syncthreads();
    }
    #pragma unroll
    for (int mt = 0; mt < 4; ++mt)
        #pragma unroll
        for (int nt = 0; nt < 2; ++nt)
            #pragma unroll
            for (int r = 0; r < 4; ++r) {
                int m = m0 + mt * 16 + lo * 4 + r;
                int n = wave * 32 + nt * 16 + ln;
                float v = acc[mt][nt][r] + bias[n];
                Out[(size_t)m * NOUT + n] = 1.f / (1.f + __expf(-v));
            }
}

extern "C" void kernel_launch(void* const* d_in, const int* in_sizes, int n_in,
                              void* d_out, int out_size, void* d_ws, size_t ws_size,
                              hipStream_t stream)
{
    const float* x   = (const float*)d_in[0];
    const float* w1  = (const float*)d_in[1];
    const float* b1  = (const float*)d_in[2];
    const float* g1  = (const float*)d_in[3];
    const float* be1 = (const float*)d_in[4];
    const float* m1  = (const float*)d_in[5];
    const float* v1  = (const float*)d_in[6];
    const float* w2  = (const float*)d_in[7];
    const float* b2  = (const float*)d_in[8];
    const float* g2  = (const float*)d_in[9];
    const float* be2 = (const float*)d_in[10];
    const float* m2  = (const float*)d_in[11];
    const float* v2  = (const float*)d_in[12];
    const float* wa  = (const float*)d_in[13];
    const float* ba  = (const float*)d_in[14];
    const float* wd1 = (const float*)d_in[15];
    const float* bd1 = (const float*)d_in[16];
    const float* wd2 = (const float*)d_in[17];
    const float* bd2 = (const float*)d_in[18];

    char* ws = (char*)d_ws;
    __bf16* f_bf   = (__bf16*)(ws);                                       // 64 MiB
    __bf16* h1_bf  = (__bf16*)(ws + 67108864);                            //  8 MiB
    __bf16* wd1_bf = (__bf16*)(ws + 67108864 + 8388608);                  //  4 MiB
    __bf16* wd2_bf = (__bf16*)(ws + 67108864 + 8388608 + 4194304);        // 128 KiB
    __bf16* w2r_bf = (__bf16*)(ws + 67108864 + 8388608 + 4194304 + 131072);     // 64 KiB slot
    __bf16* w1r_bf = (__bf16*)(ws + 67108864 + 8388608 + 4194304 + 131072 + 65536); // 8 KiB

    cvt_kernel<<<2048, 256, 0, stream>>>(wd1, wd1_bf, 512 * 4096);
    cvt_kernel<<<64, 256, 0, stream>>>(wd2, wd2_bf, 128 * 512);
    w1r_kernel<<<16, 256, 0, stream>>>(w1, w1r_bf);
    w2r_kernel<<<72, 256, 0, stream>>>(w2, w2r_bf);

    conv_fused_kernel<<<8192, 256, 0, stream>>>(x, w1r_bf, b1, g1, be1, m1, v1,
                                                w2r_bf, b2, g2, be2, m2, v2, wa, ba, f_bf);

    dim3 g3(64, 8);
    gemm1_kernel<<<g3, 256, 0, stream>>>(f_bf, wd1_bf, bd1, h1_bf);

    gemm2_kernel<<<128, 256, 0, stream>>>(h1_bf, wd2_bf, bd2, (float*)d_out);
}

// Round 6
// 314.947 us; speedup vs baseline: 2.8367x; 1.0072x over previous
//
#include <hip/hip_runtime.h>
#include <hip/hip_bf16.h>

typedef __bf16 bf16x8 __attribute__((ext_vector_type(8)));
typedef __bf16 bf16x4 __attribute__((ext_vector_type(4)));
typedef float f32x4 __attribute__((ext_vector_type(4)));

#define BN_EPS 1e-5f

// async global->LDS 16B DMA. LDS dest must be wave-uniform base + lane*16.
__device__ __forceinline__ void gl_lds16(const __bf16* g, __bf16* l) {
    __builtin_amdgcn_global_load_lds(
        (const __attribute__((address_space(1))) unsigned int*)g,
        (__attribute__((address_space(3))) unsigned int*)l,
        16, 0, 0);
}

// ---------------- P1: wd1 permute+cvt: wd1p[n][q*64+oc] = (bf16)wd1[n][oc*64+q] ----------------
__global__ __launch_bounds__(256) void wd1p_kernel(const float* __restrict__ wd1, __bf16* __restrict__ o) {
    __shared__ float t2[64][65];
    const int n = blockIdx.x;
    const int tid = threadIdx.x;
    const float* src = wd1 + (size_t)n * 4096;
    #pragma unroll
    for (int r = 0; r < 16; ++r) {
        int j = r * 256 + tid;            // j = oc*64 + q
        t2[j & 63][j >> 6] = src[j];      // t2[q][oc]
    }
    __syncthreads();
    __bf16* dst = o + (size_t)n * 4096;
    #pragma unroll
    for (int r = 0; r < 16; ++r) {
        int t = r * 256 + tid;            // t = q*64 + oc
        dst[t] = (__bf16)t2[t >> 6][t & 63];
    }
}

// ---------------- P2: combined small prep: wd2 cvt + w1 reorder + w2 reorder ----------------
__global__ void prep_kernel(const float* __restrict__ wd2, const float* __restrict__ w1,
                            const float* __restrict__ w2,
                            __bf16* __restrict__ wd2o, __bf16* __restrict__ w1o,
                            __bf16* __restrict__ w2o) {
    int i = blockIdx.x * 256 + threadIdx.x;
    if (i < 65536) { wd2o[i] = (__bf16)wd2[i]; return; }
    i -= 65536;
    if (i < 4096) {   // w1 [oc][ic][ky][kx] -> [oc][o=(ic*5+ky)][kx pad 8], K=128
        int oc = i >> 7, rem = i & 127;
        int ot = rem >> 3, j = rem & 7;
        float v = 0.f;
        if (ot < 15 && j < 5) {
            int ic = ot / 5, ky = ot % 5;
            v = w1[((oc * 3 + ic) * 5 + ky) * 5 + j];
        }
        w1o[i] = (__bf16)v;
        return;
    }
    i -= 4096;
    if (i < 18432) {  // w2 [oc][ic][tap] -> [oc][tap][ic]
        int oc = i / 288, rem = i % 288;
        int tap = rem / 32, ic = rem % 32;
        w2o[i] = (__bf16)w2[(oc * 32 + ic) * 9 + tap];
    }
}

// ---------------- K12: fused conv1(MFMA)+bn+relu + conv2(MFMA)+bn+relu + haar+attn -> f (q-major) ----------------
// one block per image, 256 threads = 4 waves. LDS 31760 B -> 5 blocks/CU.
__global__ __launch_bounds__(256, 5) void conv_fused_kernel(
    const float* __restrict__ x,
    const __bf16* __restrict__ w1r, const float* __restrict__ b1,
    const float* __restrict__ g1, const float* __restrict__ be1,
    const float* __restrict__ m1, const float* __restrict__ v1,
    const __bf16* __restrict__ w2r, const float* __restrict__ b2,
    const float* __restrict__ g2, const float* __restrict__ be2,
    const float* __restrict__ m2, const float* __restrict__ v2,
    const float* __restrict__ wa, const float* __restrict__ ba,
    __bf16* __restrict__ f)
{
    __shared__ __align__(16) __bf16 xsb[3 * 36 * 40];  // 8640 B: padded bf16 input
    __shared__ __align__(16) char  ubuf[23120];        // hs, later overlaid by feat/cd/attn
    __bf16* hsf  = (__bf16*)ubuf;                      // [pixel 17x17][ch stride 40]
    float*  feat = (float*)ubuf;                       // [64][64]
    float*  cds  = (float*)(ubuf + 16384);             // [64][16]
    float*  atn  = (float*)(ubuf + 20480);             // [4][64]

    const int b    = blockIdx.x;
    const int tid  = threadIdx.x;
    const int lane = tid & 63;
    const int wave = tid >> 6;
    const int lo   = lane >> 4;
    const int ln   = lane & 15;

    // ---- phase 0: zero xsb + hs border ----
    {
        bf16x8 z = {};
        for (int i = tid; i < 540; i += 256) *(bf16x8*)&xsb[i * 8] = z;
        if (tid < 132) {
            int pi = tid >> 2, ch = tid & 3;
            int pix = (pi < 17) ? pi : (pi - 16) * 17;
            *(bf16x8*)&hsf[pix * 40 + ch * 8] = z;
        }
    }
    __syncthreads();

    // ---- phase 1: stage x -> xsb bf16: x[ic][iy][ix] -> xsb[ic][iy+2][ix+4] ----
    {
        const float4* xb = (const float4*)(x + (size_t)b * 3072);
        #pragma unroll
        for (int r = 0; r < 3; ++r) {
            int c = r * 256 + tid;
            int plane = c >> 8, rem = c & 255;
            int row = rem >> 3, c4 = rem & 7;
            float4 v = xb[c];
            bf16x4 h;
            h[0] = (__bf16)v.x; h[1] = (__bf16)v.y; h[2] = (__bf16)v.z; h[3] = (__bf16)v.w;
            *(bf16x4*)&xsb[plane * 1440 + (row + 2) * 40 + 4 + c4 * 4] = h;
        }
    }

    // preload conv1 weights
    bf16x8 bw1[2][4];
    #pragma unroll
    for (int nt = 0; nt < 2; ++nt)
        #pragma unroll
        for (int s = 0; s < 4; ++s)
            bw1[nt][s] = *(const bf16x8*)(w1r + (nt * 16 + ln) * 128 + (s * 4 + lo) * 8);
    __syncthreads();

    // ---- phase 2: conv1 5x5 s2 p2 as MFMA (M=16 ox, N=32 oc, K=128) ----
    f32x4 c1[4][2] = {};
    const unsigned int* xw = (const unsigned int*)xsb;
    #pragma unroll
    for (int s = 0; s < 4; ++s) {
        const int o  = s * 4 + lo;
        const int ic = (o * 205) >> 10;
        const int ky = o - ic * 5;
        const bool dummy = (o == 15);
        const int icc = dummy ? 2 : ic;
        #pragma unroll
        for (int mt = 0; mt < 4; ++mt) {
            const int oy  = wave * 4 + mt;
            const int row = dummy ? 35 : (2 * oy + ky);   // row 35 always zero
            const int dw  = icc * 720 + row * 20 + ln + 1;
            union { unsigned int u[4]; bf16x8 v; } fa;
            fa.u[0] = xw[dw]; fa.u[1] = xw[dw + 1]; fa.u[2] = xw[dw + 2]; fa.u[3] = 0;
            #pragma unroll
            for (int nt = 0; nt < 2; ++nt)
                c1[mt][nt] = __builtin_amdgcn_mfma_f32_16x16x32_bf16(fa.v, bw1[nt][s], c1[mt][nt], 0, 0, 0);
        }
    }

    // ---- BN1 + ReLU -> hs (channel-last) ----
    #pragma unroll
    for (int nt = 0; nt < 2; ++nt) {
        const int oc  = nt * 16 + ln;
        const float inv = g1[oc] * rsqrtf(v1[oc] + BN_EPS);
        const float bb  = be1[oc] + (b1[oc] - m1[oc]) * inv;
        #pragma unroll
        for (int mt = 0; mt < 4; ++mt) {
            const int hy = wave * 4 + mt + 1;
            #pragma unroll
            for (int r = 0; r < 4; ++r) {
                const int hx = lo * 4 + r + 1;
                hsf[(hy * 17 + hx) * 40 + oc] = (__bf16)fmaxf(c1[mt][nt][r] * inv + bb, 0.f);
            }
        }
    }

    const int wm = wave >> 1, wn = wave & 1;
    bf16x8 bw2[2][9];
    #pragma unroll
    for (int nt = 0; nt < 2; ++nt) {
        const __bf16* wp = w2r + (wn * 32 + nt * 16 + ln) * 288 + lo * 8;
        #pragma unroll
        for (int ks = 0; ks < 9; ++ks)
            bw2[nt][ks] = *(const bf16x8*)(wp + ks * 32);
    }
    __syncthreads();

    // ---- phase 3: conv2 3x3 s2 p1 as MFMA (M=64 pix, N=64 oc, K=288) ----
    f32x4 c2[2][2] = {};
    {
        int pixbase[2];
        #pragma unroll
        for (int mt = 0; mt < 2; ++mt) {
            int p = wm * 32 + mt * 16 + ln;
            int qy = p >> 3, qx = p & 7;
            pixbase[mt] = (2 * qy * 17 + 2 * qx) * 40 + lo * 8;
        }
        #pragma unroll
        for (int ks = 0; ks < 9; ++ks) {
            const int ty = ks / 3, tx = ks % 3;
            bf16x8 af[2];
            #pragma unroll
            for (int mt = 0; mt < 2; ++mt)
                af[mt] = *(const bf16x8*)&hsf[pixbase[mt] + (ty * 17 + tx) * 40];
            #pragma unroll
            for (int mt = 0; mt < 2; ++mt)
                #pragma unroll
                for (int nt = 0; nt < 2; ++nt)
                    c2[mt][nt] = __builtin_amdgcn_mfma_f32_16x16x32_bf16(af[mt], bw2[nt][ks], c2[mt][nt], 0, 0, 0);
        }
    }
    __syncthreads();   // hs dead after this point; feat overlays it

    // ---- BN2 + ReLU -> feat[oc][pixel] ----
    #pragma unroll
    for (int nt = 0; nt < 2; ++nt) {
        const int oc  = wn * 32 + nt * 16 + ln;
        const float inv = g2[oc] * rsqrtf(v2[oc] + BN_EPS);
        const float bb  = be2[oc] + (b2[oc] - m2[oc]) * inv;
        #pragma unroll
        for (int mt = 0; mt < 2; ++mt)
            #pragma unroll
            for (int r = 0; r < 4; ++r) {
                const int p = wm * 32 + mt * 16 + lo * 4 + r;
                feat[oc * 64 + p] = fmaxf(c2[mt][nt][r] * inv + bb, 0.f);
            }
    }
    __syncthreads();

    // ---- phase 4: Haar cD ----
    #pragma unroll
    for (int r = 0; r < 4; ++r) {
        int idx = tid * 4 + r;            // 64c x 16yx
        int c = idx >> 4, yx = idx & 15;
        int y = yx >> 2, xx = yx & 3;
        float aa = feat[c * 64 + (2 * y) * 8 + 2 * xx];
        float bb = feat[c * 64 + (2 * y) * 8 + 2 * xx + 1];
        float cc = feat[c * 64 + (2 * y + 1) * 8 + 2 * xx];
        float dd = feat[c * 64 + (2 * y + 1) * 8 + 2 * xx + 1];
        cds[c * 16 + yx] = 0.5f * (aa - bb - cc + dd);
    }
    __syncthreads();

    // ---- phase 5: gating + attention ----
    const int q  = tid & 63;
    const int g  = wave;
    const int qy2 = q >> 3, qx2 = q & 7;
    const int qq = (qy2 >> 1) * 4 + (qx2 >> 1);
    float a2[16];
    float part = 0.f;
    #pragma unroll
    for (int j = 0; j < 16; ++j) {
        int oc = g * 16 + j;
        float v = feat[oc * 64 + q] * cds[oc * 16 + qq];
        a2[j] = v;
        part += v * wa[oc];
    }
    atn[g * 64 + q] = part;
    __syncthreads();
    float s2  = atn[q] + atn[64 + q] + atn[128 + q] + atn[192 + q] + ba[0];
    float sig = 1.f / (1.f + __expf(-s2));

    // ---- write f q-major: f[b][q*64 + oc], 2 x b128 per lane ----
    bf16x8 fo0, fo1;
    #pragma unroll
    for (int j = 0; j < 8; ++j) {
        fo0[j] = (__bf16)(a2[j] * sig);
        fo1[j] = (__bf16)(a2[j + 8] * sig);
    }
    __bf16* fb = f + (size_t)b * 4096 + q * 64 + g * 16;
    *(bf16x8*)fb = fo0;
    *(bf16x8*)(fb + 8) = fo1;
}

// ---------------- K3: dense1 GEMM: C[8192,512] = relu(A[8192,4096] @ B[512,4096]^T + bd1) ----------------
// tile 64(M) x 128(N), BK=64, global_load_lds + XOR swizzle. grid (128,4) = 512 blocks.
__global__ __launch_bounds__(256) void gemm1_kernel(
    const __bf16* __restrict__ A, const __bf16* __restrict__ B,
    const float* __restrict__ bias, __bf16* __restrict__ C)
{
    const int K = 4096, NOUT = 512;
    __shared__ __align__(16) __bf16 As[64][64];
    __shared__ __align__(16) __bf16 Bs[128][64];
    const int tid  = threadIdx.x;
    const int lane = tid & 63;
    const int wave = tid >> 6;
    const int lo = lane >> 4, ln = lane & 15;
    const int m0 = blockIdx.x * 64, n0 = blockIdx.y * 128;
    const int sw = ln & 7;
    f32x4 acc[4][2] = {};
    for (int k0 = 0; k0 < K; k0 += 64) {
        #pragma unroll
        for (int r = 0; r < 2; ++r) {
            int i = r * 256 + tid;
            int row = i >> 3, cs = i & 7;
            gl_lds16(A + (size_t)(m0 + row) * K + k0 + (cs ^ (row & 7)) * 8, &As[0][0] + i * 8);
        }
        #pragma unroll
        for (int r = 0; r < 4; ++r) {
            int i = r * 256 + tid;
            int row = i >> 3, cs = i & 7;
            gl_lds16(B + (size_t)(n0 + row) * K + k0 + (cs ^ (row & 7)) * 8, &Bs[0][0] + i * 8);
        }
        __syncthreads();
        #pragma unroll
        for (int s = 0; s < 2; ++s) {
            const int c = s * 4 + lo;
            const int slot = (c ^ sw) * 8;
            bf16x8 af[4], bfr[2];
            #pragma unroll
            for (int mt = 0; mt < 4; ++mt)
                af[mt] = *(const bf16x8*)(&As[mt * 16 + ln][slot]);
            #pragma unroll
            for (int nt = 0; nt < 2; ++nt)
                bfr[nt] = *(const bf16x8*)(&Bs[wave * 32 + nt * 16 + ln][slot]);
            #pragma unroll
            for (int mt = 0; mt < 4; ++mt)
                #pragma unroll
                for (int nt = 0; nt < 2; ++nt)
                    acc[mt][nt] = __builtin_amdgcn_mfma_f32_16x16x32_bf16(af[mt], bfr[nt], acc[mt][nt], 0, 0, 0);
        }
        __syncthreads();
    }
    #pragma unroll
    for (int mt = 0; mt < 4; ++mt)
        #pragma unroll
        for (int nt = 0; nt < 2; ++nt)
            #pragma unroll
            for (int r = 0; r < 4; ++r) {
                int m = m0 + mt * 16 + lo * 4 + r;
                int n = n0 + wave * 32 + nt * 16 + ln;
                float v = acc[mt][nt][r] + bias[n];
                C[(size_t)m * NOUT + n] = (__bf16)fmaxf(v, 0.f);
            }
}

// ---------------- K4: dense2: out[8192,128] = sigmoid(A[8192,512] @ B[128,512]^T + bd2) ----------------
__global__ __launch_bounds__(256) void gemm2_kernel(
    const __bf16* __restrict__ A, const __bf16* __restrict__ B,
    const float* __restrict__ bias, float* __restrict__ Out)
{
    const int K = 512, NOUT = 128;
    __shared__ __align__(16) __bf16 As[64][64];
    __shared__ __align__(16) __bf16 Bs[128][64];
    const int tid  = threadIdx.x;
    const int lane = tid & 63;
    const int wave = tid >> 6;
    const int lo = lane >> 4, ln = lane & 15;
    const int m0 = blockIdx.x * 64;
    const int sw = ln & 7;
    f32x4 acc[4][2] = {};
    for (int k0 = 0; k0 < K; k0 += 64) {
        #pragma unroll
        for (int r = 0; r < 2; ++r) {
            int i = r * 256 + tid;
            int row = i >> 3, cs = i & 7;
            gl_lds16(A + (size_t)(m0 + row) * K + k0 + (cs ^ (row & 7)) * 8, &As[0][0] + i * 8);
        }
        #pragma unroll
        for (int r = 0; r < 4; ++r) {
            int i = r * 256 + tid;
            int row = i >> 3, cs = i & 7;
            gl_lds16(B + (size_t)row * K + k0 + (cs ^ (row & 7)) * 8, &Bs[0][0] + i * 8);
        }
        __syncthreads();
        #pragma unroll
        for (int s = 0; s < 2; ++s) {
            const int c = s * 4 + lo;
            const int slot = (c ^ sw) * 8;
            bf16x8 af[4], bfr[2];
            #pragma unroll
            for (int mt = 0; mt < 4; ++mt)
                af[mt] = *(const bf16x8*)(&As[mt * 16 + ln][slot]);
            #pragma unroll
            for (int nt = 0; nt < 2; ++nt)
                bfr[nt] = *(const bf16x8*)(&Bs[wave * 32 + nt * 16 + ln][slot]);
            #pragma unroll
            for (int mt = 0; mt < 4; ++mt)
                #pragma unroll
                for (int nt = 0; nt < 2; ++nt)
                    acc[mt][nt] = __builtin_amdgcn_mfma_f32_16x16x32_bf16(af[mt], bfr[nt], acc[mt][nt], 0, 0, 0);
        }
        __syncthreads();
    }
    #pragma unroll
    for (int mt = 0; mt < 4; ++mt)
        #pragma unroll
        for (int nt = 0; nt < 2; ++nt)
            #pragma unroll
            for (int r = 0; r < 4; ++r) {
                int m = m0 + mt * 16 + lo * 4 + r;
                int n = wave * 32 + nt * 16 + ln;
                float v = acc[mt][nt][r] + bias[n];
                Out[(size_t)m * NOUT + n] = 1.f / (1.f + __expf(-v));
            }
}

extern "C" void kernel_launch(void* const* d_in, const int* in_sizes, int n_in,
                              void* d_out, int out_size, void* d_ws, size_t ws_size,
                              hipStream_t stream)
{
    const float* x   = (const float*)d_in[0];
    const float* w1  = (const float*)d_in[1];
    const float* b1  = (const float*)d_in[2];
    const float* g1  = (const float*)d_in[3];
    const float* be1 = (const float*)d_in[4];
    const float* m1  = (const float*)d_in[5];
    const float* v1  = (const float*)d_in[6];
    const float* w2  = (const float*)d_in[7];
    const float* b2  = (const float*)d_in[8];
    const float* g2  = (const float*)d_in[9];
    const float* be2 = (const float*)d_in[10];
    const float* m2  = (const float*)d_in[11];
    const float* v2  = (const float*)d_in[12];
    const float* wa  = (const float*)d_in[13];
    const float* ba  = (const float*)d_in[14];
    const float* wd1 = (const float*)d_in[15];
    const float* bd1 = (const float*)d_in[16];
    const float* wd2 = (const float*)d_in[17];
    const float* bd2 = (const float*)d_in[18];

    char* ws = (char*)d_ws;
    __bf16* f_bf   = (__bf16*)(ws);                                       // 64 MiB
    __bf16* h1_bf  = (__bf16*)(ws + 67108864);                            //  8 MiB
    __bf16* wd1_bf = (__bf16*)(ws + 67108864 + 8388608);                  //  4 MiB (permuted)
    __bf16* wd2_bf = (__bf16*)(ws + 67108864 + 8388608 + 4194304);        // 128 KiB
    __bf16* w2r_bf = (__bf16*)(ws + 67108864 + 8388608 + 4194304 + 131072);     // 64 KiB slot
    __bf16* w1r_bf = (__bf16*)(ws + 67108864 + 8388608 + 4194304 + 131072 + 65536); // 8 KiB

    prep_kernel<<<344, 256, 0, stream>>>(wd2, w1, w2, wd2_bf, w1r_bf, w2r_bf);
    wd1p_kernel<<<512, 256, 0, stream>>>(wd1, wd1_bf);

    conv_fused_kernel<<<8192, 256, 0, stream>>>(x, w1r_bf, b1, g1, be1, m1, v1,
                                                w2r_bf, b2, g2, be2, m2, v2, wa, ba, f_bf);

    dim3 g3(128, 4);
    gemm1_kernel<<<g3, 256, 0, stream>>>(f_bf, wd1_bf, bd1, h1_bf);

    gemm2_kernel<<<128, 256, 0, stream>>>(h1_bf, wd2_bf, bd2, (float*)d_out);
}